// Round 2
// baseline (908.981 us; speedup 1.0000x reference)
//
#include <hip/hip_runtime.h>
#include <cstdint>
#include <cstddef>

typedef _Float16 f16;
typedef __attribute__((ext_vector_type(4))) _Float16 f16x4;
typedef __attribute__((ext_vector_type(8))) _Float16 f16x8;
typedef __attribute__((ext_vector_type(4))) float f32x4;

#define MFMA_F16(a, b, c) __builtin_amdgcn_mfma_f32_16x16x32_f16((a), (b), (c), 0, 0, 0)

static constexpr int BB   = 8;
static constexpr int SS   = 2048;
static constexpr int DD   = 1024;
static constexpr int HALF = 512;

__device__ __forceinline__ void split4(const float4 x, f16x4& h, f16x4& l) {
  h.x = (f16)x.x; l.x = (f16)(x.x - (float)h.x);
  h.y = (f16)x.y; l.y = (f16)(x.y - (float)h.y);
  h.z = (f16)x.z; l.z = (f16)(x.z - (float)h.z);
  h.w = (f16)x.w; l.w = (f16)(x.w - (float)h.w);
}

// ---------------------------------------------------------------------------
// Split Wq, Wk into fp16 hi/lo pairs; Wv into fp16 hi only.
// ---------------------------------------------------------------------------
__global__ __launch_bounds__(256) void prep_w(
    const float* __restrict__ Wq, const float* __restrict__ Wk, const float* __restrict__ Wv,
    f16* __restrict__ Whq, f16* __restrict__ Wlq,
    f16* __restrict__ Whk, f16* __restrict__ Wlk,
    f16* __restrict__ Whv)
{
  const int i = (blockIdx.x * 256 + threadIdx.x) * 4;  // grid 1024 covers 1024*1024
  const float4 q = *(const float4*)(Wq + i);
  const float4 k = *(const float4*)(Wk + i);
  const float4 v = *(const float4*)(Wv + i);
  f16x4 qh, ql, kh, kl, vh, vl;
  split4(q, qh, ql);
  split4(k, kh, kl);
  split4(v, vh, vl);
  *(f16x4*)(Whq + i) = qh;
  *(f16x4*)(Wlq + i) = ql;
  *(f16x4*)(Whk + i) = kh;
  *(f16x4*)(Wlk + i) = kl;
  *(f16x4*)(Whv + i) = vh;
}

// ---------------------------------------------------------------------------
// QKV projection for a chunk of batches starting at b0.
// C[m][n] = sum_k X[b0*S + m][k] * W[n][k] + bias[n], m local to chunk.
// z = 0: Q (3-term split), z = 1: K (3-term), z = 2: V (1-term).
// ---------------------------------------------------------------------------
__global__ __launch_bounds__(256) void proj_gemm(
    const float* __restrict__ t_out, const float* __restrict__ c_out,
    const f16* __restrict__ Whq, const f16* __restrict__ Wlq,
    const f16* __restrict__ Whk, const f16* __restrict__ Wlk,
    const f16* __restrict__ Whv,
    const float* __restrict__ bq, const float* __restrict__ bk, const float* __restrict__ bv,
    f16* __restrict__ Qhi, f16* __restrict__ Qlo,
    f16* __restrict__ Khi, f16* __restrict__ Klo,
    f16* __restrict__ Vv, int b0)
{
  __shared__ alignas(16) f16 Ah[128 * 32];
  __shared__ alignas(16) f16 Al[128 * 32];
  __shared__ alignas(16) f16 Bh[128 * 32];
  __shared__ alignas(16) f16 Bl[128 * 32];

  const int z = blockIdx.z;
  const f16* Wh = (z == 0) ? Whq : (z == 1) ? Whk : Whv;
  const f16* Wl = (z == 0) ? Wlq : Wlk;  // unused when z == 2
  const float* bias = (z == 0) ? bq : (z == 1) ? bk : bv;
  const bool split = (z < 2);

  const int t    = threadIdx.x;
  const int srow = t >> 1;          // 0..127
  const int scol = (t & 1) << 4;    // 0 or 16
  const int m0   = blockIdx.y * 128;   // local token row
  const int n0   = blockIdx.x * 128;
  const int lane = t & 63;
  const int wave = t >> 6;
  const int wm   = (wave & 1) << 6;
  const int wn   = (wave >> 1) << 6;
  const int col  = lane & 15;
  const int quad = lane >> 4;

  f32x4 acc[4][4];
#pragma unroll
  for (int i = 0; i < 4; ++i)
#pragma unroll
    for (int j = 0; j < 4; ++j)
      acc[i][j] = f32x4{0.f, 0.f, 0.f, 0.f};

  for (int k0 = 0; k0 < DD; k0 += 32) {
    // stage A: X rows (global), cols k0..k0+31 (fp32 -> hi/lo fp16)
    {
      const size_t g = (size_t)b0 * SS + (size_t)(m0 + srow);  // global token
#pragma unroll
      for (int u = 0; u < 4; ++u) {
        const int kk = scol + u * 4;
        const int kd = k0 + kk;
        const float* src = (kd < HALF) ? (t_out + g * HALF + kd)
                                       : (c_out + g * HALF + (kd - HALF));
        const float4 x = *(const float4*)src;
        f16x4 hv, lv;
        split4(x, hv, lv);
        *(f16x4*)&Ah[srow * 32 + kk] = hv;
        if (split) *(f16x4*)&Al[srow * 32 + kk] = lv;
      }
    }
    // stage B: W rows n0..n0+127 (pre-split fp16)
    {
      const size_t n = (size_t)(n0 + srow);
      const f16* ph = Wh + n * DD + k0 + scol;
      *(int4*)&Bh[srow * 32 + scol]     = *(const int4*)ph;
      *(int4*)&Bh[srow * 32 + scol + 8] = *(const int4*)(ph + 8);
      if (split) {
        const f16* pl = Wl + n * DD + k0 + scol;
        *(int4*)&Bl[srow * 32 + scol]     = *(const int4*)pl;
        *(int4*)&Bl[srow * 32 + scol + 8] = *(const int4*)(pl + 8);
      }
    }
    __syncthreads();

    f16x8 ah[4], bh[4];
#pragma unroll
    for (int i = 0; i < 4; ++i) ah[i] = *(const f16x8*)&Ah[(wm + i * 16 + col) * 32 + quad * 8];
#pragma unroll
    for (int j = 0; j < 4; ++j) bh[j] = *(const f16x8*)&Bh[(wn + j * 16 + col) * 32 + quad * 8];
#pragma unroll
    for (int i = 0; i < 4; ++i)
#pragma unroll
      for (int j = 0; j < 4; ++j)
        acc[i][j] = MFMA_F16(ah[i], bh[j], acc[i][j]);

    if (split) {
      f16x8 al[4], bl[4];
#pragma unroll
      for (int i = 0; i < 4; ++i) al[i] = *(const f16x8*)&Al[(wm + i * 16 + col) * 32 + quad * 8];
#pragma unroll
      for (int j = 0; j < 4; ++j) bl[j] = *(const f16x8*)&Bl[(wn + j * 16 + col) * 32 + quad * 8];
#pragma unroll
      for (int i = 0; i < 4; ++i)
#pragma unroll
        for (int j = 0; j < 4; ++j) {
          acc[i][j] = MFMA_F16(ah[i], bl[j], acc[i][j]);
          acc[i][j] = MFMA_F16(al[i], bh[j], acc[i][j]);
        }
    }
    __syncthreads();
  }

  // epilogue: C/D layout row = quad*4+r (M dim), col = lane&15 (N dim)
#pragma unroll
  for (int j = 0; j < 4; ++j) {
    const int gn = n0 + wn + j * 16 + col;
    const float bb = bias[gn];
#pragma unroll
    for (int i = 0; i < 4; ++i) {
#pragma unroll
      for (int r = 0; r < 4; ++r) {
        const int gm = m0 + wm + i * 16 + quad * 4 + r;  // local token row
        const float c = acc[i][j][r] + bb;
        const size_t idx = (size_t)gm * DD + gn;
        if (z == 0) {
          const f16 h = (f16)c;
          Qhi[idx] = h;
          Qlo[idx] = (f16)(c - (float)h);
        } else if (z == 1) {
          const f16 h = (f16)c;
          Khi[idx] = h;
          Klo[idx] = (f16)(c - (float)h);
        } else {
          Vv[idx] = (f16)c;
        }
      }
    }
  }
}

// ---------------------------------------------------------------------------
// Transpose V [bb][s][e] -> Vt [bb][e][s]  (chunk-local)
// ---------------------------------------------------------------------------
__global__ __launch_bounds__(256) void transpose_v(
    const f16* __restrict__ Vv, f16* __restrict__ Vt)
{
  __shared__ alignas(16) f16 tile[64][72];  // +8 pad
  const int bb = blockIdx.z;
  const int s0 = blockIdx.x * 64;
  const int e0 = blockIdx.y * 64;
  const int t  = threadIdx.x;
  const int r  = t >> 3;        // 0..31
  const int c8 = (t & 7) * 8;   // 0..56

  const f16* src0 = Vv + ((size_t)(bb * SS + s0 + r)) * DD + e0 + c8;
  const f16* src1 = Vv + ((size_t)(bb * SS + s0 + r + 32)) * DD + e0 + c8;
  *(int4*)&tile[r][c8]      = *(const int4*)src0;
  *(int4*)&tile[r + 32][c8] = *(const int4*)src1;
  __syncthreads();

  f16x8 v0, v1;
#pragma unroll
  for (int u = 0; u < 8; ++u) {
    v0[u] = tile[c8 + u][r];
    v1[u] = tile[c8 + u][r + 32];
  }
  f16* dst0 = Vt + ((size_t)bb * DD + e0 + r) * SS + s0 + c8;
  f16* dst1 = Vt + ((size_t)bb * DD + e0 + r + 32) * SS + s0 + c8;
  *(f16x8*)dst0 = v0;
  *(f16x8*)dst1 = v1;
}

// ---------------------------------------------------------------------------
// Scores (chunk-local): Sc[bb][i][j] = sum_d Q[bb*S+i][d] * K[bb*S+j][d]
// ---------------------------------------------------------------------------
__global__ __launch_bounds__(256) void qk_gemm(
    const f16* __restrict__ Qhi, const f16* __restrict__ Qlo,
    const f16* __restrict__ Khi, const f16* __restrict__ Klo,
    float* __restrict__ Sc)
{
  __shared__ alignas(16) f16 Ah[128 * 32];
  __shared__ alignas(16) f16 Al[128 * 32];
  __shared__ alignas(16) f16 Bh[128 * 32];
  __shared__ alignas(16) f16 Bl[128 * 32];

  const int bb   = blockIdx.z;
  const int t    = threadIdx.x;
  const int srow = t >> 1;
  const int scol = (t & 1) << 4;
  const int m0   = blockIdx.y * 128;
  const int n0   = blockIdx.x * 128;
  const int lane = t & 63;
  const int wave = t >> 6;
  const int wm   = (wave & 1) << 6;
  const int wn   = (wave >> 1) << 6;
  const int col  = lane & 15;
  const int quad = lane >> 4;

  const size_t arow0 = (size_t)(bb * SS + m0);
  const size_t brow0 = (size_t)(bb * SS + n0);

  f32x4 acc[4][4];
#pragma unroll
  for (int i = 0; i < 4; ++i)
#pragma unroll
    for (int j = 0; j < 4; ++j)
      acc[i][j] = f32x4{0.f, 0.f, 0.f, 0.f};

  for (int k0 = 0; k0 < DD; k0 += 32) {
    const size_t ar = (arow0 + srow) * DD + k0 + scol;
    *(int4*)&Ah[srow * 32 + scol]     = *(const int4*)(Qhi + ar);
    *(int4*)&Ah[srow * 32 + scol + 8] = *(const int4*)(Qhi + ar + 8);
    *(int4*)&Al[srow * 32 + scol]     = *(const int4*)(Qlo + ar);
    *(int4*)&Al[srow * 32 + scol + 8] = *(const int4*)(Qlo + ar + 8);
    const size_t br = (brow0 + srow) * DD + k0 + scol;
    *(int4*)&Bh[srow * 32 + scol]     = *(const int4*)(Khi + br);
    *(int4*)&Bh[srow * 32 + scol + 8] = *(const int4*)(Khi + br + 8);
    *(int4*)&Bl[srow * 32 + scol]     = *(const int4*)(Klo + br);
    *(int4*)&Bl[srow * 32 + scol + 8] = *(const int4*)(Klo + br + 8);
    __syncthreads();

    f16x8 ah[4], bh[4], al[4], bl[4];
#pragma unroll
    for (int i = 0; i < 4; ++i) {
      ah[i] = *(const f16x8*)&Ah[(wm + i * 16 + col) * 32 + quad * 8];
      al[i] = *(const f16x8*)&Al[(wm + i * 16 + col) * 32 + quad * 8];
    }
#pragma unroll
    for (int j = 0; j < 4; ++j) {
      bh[j] = *(const f16x8*)&Bh[(wn + j * 16 + col) * 32 + quad * 8];
      bl[j] = *(const f16x8*)&Bl[(wn + j * 16 + col) * 32 + quad * 8];
    }
#pragma unroll
    for (int i = 0; i < 4; ++i)
#pragma unroll
      for (int j = 0; j < 4; ++j) {
        acc[i][j] = MFMA_F16(ah[i], bh[j], acc[i][j]);
        acc[i][j] = MFMA_F16(ah[i], bl[j], acc[i][j]);
        acc[i][j] = MFMA_F16(al[i], bh[j], acc[i][j]);
      }
    __syncthreads();
  }

#pragma unroll
  for (int i = 0; i < 4; ++i)
#pragma unroll
    for (int j = 0; j < 4; ++j)
#pragma unroll
      for (int r = 0; r < 4; ++r) {
        const int gm = m0 + wm + i * 16 + quad * 4 + r;
        const int gn = n0 + wn + j * 16 + col;
        Sc[((size_t)bb * SS + gm) * SS + gn] = acc[i][j][r];
      }
}

// ---------------------------------------------------------------------------
// Row softmax over fp32 scores -> normalized fp16 P (chunk-local rows)
// ---------------------------------------------------------------------------
__global__ __launch_bounds__(256) void softmax_rows(
    const float* __restrict__ Sc, f16* __restrict__ P)
{
  const size_t row = blockIdx.x;
  const float* src = Sc + row * SS;
  const int t = threadIdx.x;

  const float4 x0 = *(const float4*)(src + t * 4);
  const float4 x1 = *(const float4*)(src + 1024 + t * 4);
  float xs[8] = {x0.x, x0.y, x0.z, x0.w, x1.x, x1.y, x1.z, x1.w};

  float m = xs[0];
#pragma unroll
  for (int u = 1; u < 8; ++u) m = fmaxf(m, xs[u]);
#pragma unroll
  for (int off = 32; off > 0; off >>= 1) m = fmaxf(m, __shfl_xor(m, off));
  __shared__ float redm[4];
  __shared__ float reds[4];
  if ((t & 63) == 0) redm[t >> 6] = m;
  __syncthreads();
  m = fmaxf(fmaxf(redm[0], redm[1]), fmaxf(redm[2], redm[3]));

  float e[8];
  float s = 0.f;
#pragma unroll
  for (int u = 0; u < 8; ++u) {
    e[u] = expf(xs[u] - m);
    s += e[u];
  }
#pragma unroll
  for (int off = 32; off > 0; off >>= 1) s += __shfl_xor(s, off);
  if ((t & 63) == 0) reds[t >> 6] = s;
  __syncthreads();
  s = reds[0] + reds[1] + reds[2] + reds[3];
  const float inv = 1.0f / s;

  f16x4 o0, o1;
  o0.x = (f16)(e[0] * inv); o0.y = (f16)(e[1] * inv);
  o0.z = (f16)(e[2] * inv); o0.w = (f16)(e[3] * inv);
  o1.x = (f16)(e[4] * inv); o1.y = (f16)(e[5] * inv);
  o1.z = (f16)(e[6] * inv); o1.w = (f16)(e[7] * inv);
  *(f16x4*)(P + row * SS + t * 4)        = o0;
  *(f16x4*)(P + row * SS + 1024 + t * 4) = o1;
}

// ---------------------------------------------------------------------------
// Output: out[b0+bb][s][e] = sum_j P[bb][s][j] * Vt[bb][e][j]   (fp32 out)
// ---------------------------------------------------------------------------
__global__ __launch_bounds__(256) void pv_gemm(
    const f16* __restrict__ P, const f16* __restrict__ Vt, float* __restrict__ out,
    int b0)
{
  __shared__ alignas(16) f16 Ah[128 * 32];
  __shared__ alignas(16) f16 Bh[128 * 32];

  const int bb   = blockIdx.z;
  const int t    = threadIdx.x;
  const int srow = t >> 1;
  const int scol = (t & 1) << 4;
  const int m0   = blockIdx.y * 128;  // s
  const int n0   = blockIdx.x * 128;  // e
  const int lane = t & 63;
  const int wave = t >> 6;
  const int wm   = (wave & 1) << 6;
  const int wn   = (wave >> 1) << 6;
  const int col  = lane & 15;
  const int quad = lane >> 4;

  const size_t arow0 = (size_t)bb * SS + m0;  // P rows (s), chunk-local
  const size_t brow0 = (size_t)bb * DD + n0;  // Vt rows (e), chunk-local

  f32x4 acc[4][4];
#pragma unroll
  for (int i = 0; i < 4; ++i)
#pragma unroll
    for (int j = 0; j < 4; ++j)
      acc[i][j] = f32x4{0.f, 0.f, 0.f, 0.f};

  for (int k0 = 0; k0 < SS; k0 += 32) {
    const size_t ar = (arow0 + srow) * SS + k0 + scol;
    *(int4*)&Ah[srow * 32 + scol]     = *(const int4*)(P + ar);
    *(int4*)&Ah[srow * 32 + scol + 8] = *(const int4*)(P + ar + 8);
    const size_t br = (brow0 + srow) * SS + k0 + scol;
    *(int4*)&Bh[srow * 32 + scol]     = *(const int4*)(Vt + br);
    *(int4*)&Bh[srow * 32 + scol + 8] = *(const int4*)(Vt + br + 8);
    __syncthreads();

    f16x8 ah[4], bh[4];
#pragma unroll
    for (int i = 0; i < 4; ++i) ah[i] = *(const f16x8*)&Ah[(wm + i * 16 + col) * 32 + quad * 8];
#pragma unroll
    for (int j = 0; j < 4; ++j) bh[j] = *(const f16x8*)&Bh[(wn + j * 16 + col) * 32 + quad * 8];
#pragma unroll
    for (int i = 0; i < 4; ++i)
#pragma unroll
      for (int j = 0; j < 4; ++j)
        acc[i][j] = MFMA_F16(ah[i], bh[j], acc[i][j]);
    __syncthreads();
  }

#pragma unroll
  for (int i = 0; i < 4; ++i)
#pragma unroll
    for (int j = 0; j < 4; ++j)
#pragma unroll
      for (int r = 0; r < 4; ++r) {
        const int gm = m0 + wm + i * 16 + quad * 4 + r;
        const int gn = n0 + wn + j * 16 + col;
        out[((size_t)(b0 + bb) * SS + gm) * DD + gn] = acc[i][j][r];
      }
}

// ---------------------------------------------------------------------------
extern "C" void kernel_launch(void* const* d_in, const int* in_sizes, int n_in,
                              void* d_out, int out_size, void* d_ws, size_t ws_size,
                              hipStream_t stream)
{
  const float* t_out = (const float*)d_in[0];
  const float* c_out = (const float*)d_in[1];
  const float* Wq    = (const float*)d_in[2];
  const float* bq    = (const float*)d_in[3];
  const float* Wk    = (const float*)d_in[4];
  const float* bk    = (const float*)d_in[5];
  const float* Wv    = (const float*)d_in[6];
  const float* bv    = (const float*)d_in[7];
  float* out = (float*)d_out;

  // ---- workspace budget ----
  const size_t WELT   = (size_t)DD * DD;            // 1,048,576
  const size_t SDELT  = (size_t)SS * DD;            // 2,097,152 (per batch)
  const size_t WBYTES = 5 * WELT * sizeof(f16);     // 10 MB
  const size_t PB     = 6 * SDELT * sizeof(f16)     // Qhi,Qlo,Khi,Klo,Vv,Vt
                      + (size_t)SS * SS * sizeof(float);  // Sc
  int c = 1;
  for (int cand : {8, 4, 2}) {
    if (WBYTES + (size_t)cand * PB <= ws_size) { c = cand; break; }
  }

  // ---- layout: [weights][Qhi|Qlo|Khi|Klo|Vv|Vt][Sc], P aliases Qhi+Qlo ----
  char* ws = (char*)d_ws;
  f16* Whq = (f16*)ws;
  f16* Wlq = Whq + WELT;
  f16* Whk = Wlq + WELT;
  f16* Wlk = Whk + WELT;
  f16* Whv = Wlk + WELT;
  f16* Qhi = Whv + WELT;
  f16* Qlo = Qhi + (size_t)c * SDELT;
  f16* Khi = Qlo + (size_t)c * SDELT;
  f16* Klo = Khi + (size_t)c * SDELT;
  f16* Vv  = Klo + (size_t)c * SDELT;
  f16* Vt  = Vv  + (size_t)c * SDELT;
  float* Sc = (float*)(Vt + (size_t)c * SDELT);
  f16* P   = Qhi;  // Qhi+Qlo dead after qk_gemm; size matches exactly

  prep_w<<<dim3(1024), dim3(256), 0, stream>>>(Wq, Wk, Wv, Whq, Wlq, Whk, Wlk, Whv);

  for (int b0 = 0; b0 < BB; b0 += c) {
    proj_gemm<<<dim3(8, c * 16, 3), dim3(256), 0, stream>>>(
        t_out, c_out, Whq, Wlq, Whk, Wlk, Whv, bq, bk, bv,
        Qhi, Qlo, Khi, Klo, Vv, b0);
    transpose_v<<<dim3(32, 16, c), dim3(256), 0, stream>>>(Vv, Vt);
    qk_gemm<<<dim3(16, 16, c), dim3(256), 0, stream>>>(Qhi, Qlo, Khi, Klo, Sc);
    softmax_rows<<<dim3(c * SS), dim3(256), 0, stream>>>(Sc, P);
    pv_gemm<<<dim3(8, 16, c), dim3(256), 0, stream>>>(P, Vt, out, b0);
  }
}

// Round 3
// 732.464 us; speedup vs baseline: 1.2410x; 1.2410x over previous
//
#include <hip/hip_runtime.h>
#include <cstdint>
#include <cstddef>

typedef _Float16 f16;
typedef __attribute__((ext_vector_type(4))) _Float16 f16x4;
typedef __attribute__((ext_vector_type(8))) _Float16 f16x8;
typedef __attribute__((ext_vector_type(4))) float f32x4;

#define MFMA_F16(a, b, c) __builtin_amdgcn_mfma_f32_16x16x32_f16((a), (b), (c), 0, 0, 0)

static constexpr int BB   = 8;
static constexpr int SS   = 2048;
static constexpr int DD   = 1024;
static constexpr int HALF = 512;

// async global->LDS, 16 B per lane; LDS dest must be wave-uniform base
// (HW writes base + lane*16). [m97 pattern]
__device__ __forceinline__ void gll16(const f16* g, f16* lds) {
  __builtin_amdgcn_global_load_lds(
      (__attribute__((address_space(1))) void*)(g),
      (__attribute__((address_space(3))) void*)(lds), 16, 0, 0);
}

__device__ __forceinline__ void split4(const float4 x, f16x4& h, f16x4& l) {
  h.x = (f16)x.x; l.x = (f16)(x.x - (float)h.x);
  h.y = (f16)x.y; l.y = (f16)(x.y - (float)h.y);
  h.z = (f16)x.z; l.z = (f16)(x.z - (float)h.z);
  h.w = (f16)x.w; l.w = (f16)(x.w - (float)h.w);
}

// ---------------------------------------------------------------------------
// Weights: fp16 hi only (x is split instead; dropped x*Wl term ~8e-5/elem)
// ---------------------------------------------------------------------------
__global__ __launch_bounds__(256) void prep_w(
    const float* __restrict__ Wq, const float* __restrict__ Wk, const float* __restrict__ Wv,
    f16* __restrict__ Whq, f16* __restrict__ Whk, f16* __restrict__ Whv)
{
  const int i = (blockIdx.x * 256 + threadIdx.x) * 4;
  const float4 q = *(const float4*)(Wq + i);
  const float4 k = *(const float4*)(Wk + i);
  const float4 v = *(const float4*)(Wv + i);
  f16x4 a, b;
  split4(q, a, b); *(f16x4*)(Whq + i) = a;
  split4(k, a, b); *(f16x4*)(Whk + i) = a;
  split4(v, a, b); *(f16x4*)(Whv + i) = a;
}

// ---------------------------------------------------------------------------
// X = concat(t_out, c_out) for chunk tokens, split to fp16 hi/lo.
// ---------------------------------------------------------------------------
__global__ __launch_bounds__(256) void prep_x(
    const float* __restrict__ t_out, const float* __restrict__ c_out,
    f16* __restrict__ Xh, f16* __restrict__ Xl, int b0)
{
  const size_t i = ((size_t)blockIdx.x * 256 + threadIdx.x) * 4;
  const int d = (int)(i & 1023);
  const size_t g = (size_t)b0 * SS + (i >> 10);
  const float* src = (d < HALF) ? (t_out + g * HALF + d)
                                : (c_out + g * HALF + (d - HALF));
  const float4 x = *(const float4*)src;
  f16x4 h, l;
  split4(x, h, l);
  *(f16x4*)(Xh + i) = h;
  *(f16x4*)(Xl + i) = l;
}

// ---------------------------------------------------------------------------
// stage one 128x32-f16 LDS tile (8 KB) from row-major global [row][ld]
// rows src0..src0+127, cols k0..k0+31. Call with all 256 threads.
// ---------------------------------------------------------------------------
__device__ __forceinline__ void stage_tile(
    f16* lds, const f16* g, size_t row0, int ld, int k0, int wave, int lane)
{
  const int lrow = lane >> 2;          // 0..15
  const int lq8  = (lane & 3) << 3;    // 0,8,16,24 (f16)
#pragma unroll
  for (int r = 0; r < 2; ++r) {
    const int rb = r * 64 + wave * 16;  // wave-uniform
    gll16(g + (row0 + (size_t)(rb + lrow)) * ld + k0 + lq8, lds + rb * 32);
  }
}

// ---------------------------------------------------------------------------
// QKV projection. z=0: Q = x*Whq (2 MFMA, x split), store hi/lo.
//                 z=1: K = x*Whk (2 MFMA), store hi only.
//                 z=2: V = xh*Whv (1 MFMA), store hi only.
// ---------------------------------------------------------------------------
__global__ __launch_bounds__(256) void proj_gemm(
    const f16* __restrict__ Xh, const f16* __restrict__ Xl,
    const f16* __restrict__ Whq, const f16* __restrict__ Whk, const f16* __restrict__ Whv,
    const float* __restrict__ bq, const float* __restrict__ bk, const float* __restrict__ bv,
    f16* __restrict__ Qhi, f16* __restrict__ Qlo,
    f16* __restrict__ Khi, f16* __restrict__ Vv)
{
  __shared__ alignas(16) f16 Ah[128 * 32];
  __shared__ alignas(16) f16 Al[128 * 32];
  __shared__ alignas(16) f16 Bh[128 * 32];

  const int z = blockIdx.z;
  const f16* Wh = (z == 0) ? Whq : (z == 1) ? Whk : Whv;
  const float* bias = (z == 0) ? bq : (z == 1) ? bk : bv;
  const bool split = (z < 2);

  const int t    = threadIdx.x;
  const int m0   = blockIdx.y * 128;   // chunk-local token row
  const int n0   = blockIdx.x * 128;
  const int lane = t & 63;
  const int wave = t >> 6;
  const int wm   = (wave & 1) << 6;
  const int wn   = (wave >> 1) << 6;
  const int col  = lane & 15;
  const int quad = lane >> 4;

  f32x4 acc[4][4];
#pragma unroll
  for (int i = 0; i < 4; ++i)
#pragma unroll
    for (int j = 0; j < 4; ++j)
      acc[i][j] = f32x4{0.f, 0.f, 0.f, 0.f};

  for (int k0 = 0; k0 < DD; k0 += 32) {
    stage_tile(Ah, Xh, (size_t)m0, DD, k0, wave, lane);
    if (split) stage_tile(Al, Xl, (size_t)m0, DD, k0, wave, lane);
    stage_tile(Bh, Wh, (size_t)n0, DD, k0, wave, lane);
    __syncthreads();

    f16x8 ah[4], bh[4];
#pragma unroll
    for (int i = 0; i < 4; ++i) ah[i] = *(const f16x8*)&Ah[(wm + i * 16 + col) * 32 + quad * 8];
#pragma unroll
    for (int j = 0; j < 4; ++j) bh[j] = *(const f16x8*)&Bh[(wn + j * 16 + col) * 32 + quad * 8];
#pragma unroll
    for (int i = 0; i < 4; ++i)
#pragma unroll
      for (int j = 0; j < 4; ++j)
        acc[i][j] = MFMA_F16(ah[i], bh[j], acc[i][j]);

    if (split) {
      f16x8 al[4];
#pragma unroll
      for (int i = 0; i < 4; ++i) al[i] = *(const f16x8*)&Al[(wm + i * 16 + col) * 32 + quad * 8];
#pragma unroll
      for (int i = 0; i < 4; ++i)
#pragma unroll
        for (int j = 0; j < 4; ++j)
          acc[i][j] = MFMA_F16(al[i], bh[j], acc[i][j]);
    }
    __syncthreads();
  }

  // epilogue: C/D row = quad*4+r (M), col = lane&15 (N)
#pragma unroll
  for (int j = 0; j < 4; ++j) {
    const int gn = n0 + wn + j * 16 + col;
    const float bb = bias[gn];
#pragma unroll
    for (int i = 0; i < 4; ++i) {
#pragma unroll
      for (int r = 0; r < 4; ++r) {
        const int gm = m0 + wm + i * 16 + quad * 4 + r;
        const float c = acc[i][j][r] + bb;
        const size_t idx = (size_t)gm * DD + gn;
        if (z == 0) {
          const f16 h = (f16)c;
          Qhi[idx] = h;
          Qlo[idx] = (f16)(c - (float)h);
        } else if (z == 1) {
          Khi[idx] = (f16)c;
        } else {
          Vv[idx] = (f16)c;
        }
      }
    }
  }
}

// ---------------------------------------------------------------------------
// Transpose V [bb][s][e] -> Vt [bb][e][s]
// ---------------------------------------------------------------------------
__global__ __launch_bounds__(256) void transpose_v(
    const f16* __restrict__ Vv, f16* __restrict__ Vt)
{
  __shared__ alignas(16) f16 tile[64][72];
  const int bb = blockIdx.z;
  const int s0 = blockIdx.x * 64;
  const int e0 = blockIdx.y * 64;
  const int t  = threadIdx.x;
  const int r  = t >> 3;
  const int c8 = (t & 7) * 8;

  const f16* src0 = Vv + ((size_t)(bb * SS + s0 + r)) * DD + e0 + c8;
  const f16* src1 = Vv + ((size_t)(bb * SS + s0 + r + 32)) * DD + e0 + c8;
  *(int4*)&tile[r][c8]      = *(const int4*)src0;
  *(int4*)&tile[r + 32][c8] = *(const int4*)src1;
  __syncthreads();

  f16x8 v0, v1;
#pragma unroll
  for (int u = 0; u < 8; ++u) {
    v0[u] = tile[c8 + u][r];
    v1[u] = tile[c8 + u][r + 32];
  }
  f16* dst0 = Vt + ((size_t)bb * DD + e0 + r) * SS + s0 + c8;
  f16* dst1 = Vt + ((size_t)bb * DD + e0 + r + 32) * SS + s0 + c8;
  *(f16x8*)dst0 = v0;
  *(f16x8*)dst1 = v1;
}

// ---------------------------------------------------------------------------
// Scores: Sc = (qh+ql) . kh   (2 MFMA per fragment pair; exact-q x fp16-k)
// ---------------------------------------------------------------------------
__global__ __launch_bounds__(256) void qk_gemm(
    const f16* __restrict__ Qhi, const f16* __restrict__ Qlo,
    const f16* __restrict__ Khi, float* __restrict__ Sc)
{
  __shared__ alignas(16) f16 Ah[128 * 32];
  __shared__ alignas(16) f16 Al[128 * 32];
  __shared__ alignas(16) f16 Bh[128 * 32];

  const int bb   = blockIdx.z;
  const int t    = threadIdx.x;
  const int m0   = blockIdx.y * 128;
  const int n0   = blockIdx.x * 128;
  const int lane = t & 63;
  const int wave = t >> 6;
  const int wm   = (wave & 1) << 6;
  const int wn   = (wave >> 1) << 6;
  const int col  = lane & 15;
  const int quad = lane >> 4;

  const size_t arow0 = (size_t)(bb * SS + m0);
  const size_t brow0 = (size_t)(bb * SS + n0);

  f32x4 acc[4][4];
#pragma unroll
  for (int i = 0; i < 4; ++i)
#pragma unroll
    for (int j = 0; j < 4; ++j)
      acc[i][j] = f32x4{0.f, 0.f, 0.f, 0.f};

  for (int k0 = 0; k0 < DD; k0 += 32) {
    stage_tile(Ah, Qhi, arow0, DD, k0, wave, lane);
    stage_tile(Al, Qlo, arow0, DD, k0, wave, lane);
    stage_tile(Bh, Khi, brow0, DD, k0, wave, lane);
    __syncthreads();

    f16x8 ah[4], al[4], bh[4];
#pragma unroll
    for (int i = 0; i < 4; ++i) {
      ah[i] = *(const f16x8*)&Ah[(wm + i * 16 + col) * 32 + quad * 8];
      al[i] = *(const f16x8*)&Al[(wm + i * 16 + col) * 32 + quad * 8];
    }
#pragma unroll
    for (int j = 0; j < 4; ++j)
      bh[j] = *(const f16x8*)&Bh[(wn + j * 16 + col) * 32 + quad * 8];
#pragma unroll
    for (int i = 0; i < 4; ++i)
#pragma unroll
      for (int j = 0; j < 4; ++j) {
        acc[i][j] = MFMA_F16(ah[i], bh[j], acc[i][j]);
        acc[i][j] = MFMA_F16(al[i], bh[j], acc[i][j]);
      }
    __syncthreads();
  }

#pragma unroll
  for (int i = 0; i < 4; ++i)
#pragma unroll
    for (int j = 0; j < 4; ++j)
#pragma unroll
      for (int r = 0; r < 4; ++r) {
        const int gm = m0 + wm + i * 16 + quad * 4 + r;
        const int gn = n0 + wn + j * 16 + col;
        Sc[((size_t)bb * SS + gm) * SS + gn] = acc[i][j][r];
      }
}

// ---------------------------------------------------------------------------
// Row softmax fp32 -> normalized fp16 P
// ---------------------------------------------------------------------------
__global__ __launch_bounds__(256) void softmax_rows(
    const float* __restrict__ Sc, f16* __restrict__ P)
{
  const size_t row = blockIdx.x;
  const float* src = Sc + row * SS;
  const int t = threadIdx.x;

  const float4 x0 = *(const float4*)(src + t * 4);
  const float4 x1 = *(const float4*)(src + 1024 + t * 4);
  float xs[8] = {x0.x, x0.y, x0.z, x0.w, x1.x, x1.y, x1.z, x1.w};

  float m = xs[0];
#pragma unroll
  for (int u = 1; u < 8; ++u) m = fmaxf(m, xs[u]);
#pragma unroll
  for (int off = 32; off > 0; off >>= 1) m = fmaxf(m, __shfl_xor(m, off));
  __shared__ float redm[4];
  __shared__ float reds[4];
  if ((t & 63) == 0) redm[t >> 6] = m;
  __syncthreads();
  m = fmaxf(fmaxf(redm[0], redm[1]), fmaxf(redm[2], redm[3]));

  float e[8];
  float s = 0.f;
#pragma unroll
  for (int u = 0; u < 8; ++u) {
    e[u] = expf(xs[u] - m);
    s += e[u];
  }
#pragma unroll
  for (int off = 32; off > 0; off >>= 1) s += __shfl_xor(s, off);
  if ((t & 63) == 0) reds[t >> 6] = s;
  __syncthreads();
  s = reds[0] + reds[1] + reds[2] + reds[3];
  const float inv = 1.0f / s;

  f16x4 o0, o1;
  o0.x = (f16)(e[0] * inv); o0.y = (f16)(e[1] * inv);
  o0.z = (f16)(e[2] * inv); o0.w = (f16)(e[3] * inv);
  o1.x = (f16)(e[4] * inv); o1.y = (f16)(e[5] * inv);
  o1.z = (f16)(e[6] * inv); o1.w = (f16)(e[7] * inv);
  *(f16x4*)(P + row * SS + t * 4)        = o0;
  *(f16x4*)(P + row * SS + 1024 + t * 4) = o1;
}

// ---------------------------------------------------------------------------
// Output: out[b0+bb][s][e] = sum_j P[bb][s][j] * Vt[bb][e][j]
// ---------------------------------------------------------------------------
__global__ __launch_bounds__(256) void pv_gemm(
    const f16* __restrict__ P, const f16* __restrict__ Vt, float* __restrict__ out,
    int b0)
{
  __shared__ alignas(16) f16 Ah[128 * 32];
  __shared__ alignas(16) f16 Bh[128 * 32];

  const int bb   = blockIdx.z;
  const int t    = threadIdx.x;
  const int m0   = blockIdx.y * 128;  // s
  const int n0   = blockIdx.x * 128;  // e
  const int lane = t & 63;
  const int wave = t >> 6;
  const int wm   = (wave & 1) << 6;
  const int wn   = (wave >> 1) << 6;
  const int col  = lane & 15;
  const int quad = lane >> 4;

  const size_t arow0 = (size_t)bb * SS + m0;
  const size_t brow0 = (size_t)bb * DD + n0;

  f32x4 acc[4][4];
#pragma unroll
  for (int i = 0; i < 4; ++i)
#pragma unroll
    for (int j = 0; j < 4; ++j)
      acc[i][j] = f32x4{0.f, 0.f, 0.f, 0.f};

  for (int k0 = 0; k0 < SS; k0 += 32) {
    stage_tile(Ah, P, arow0, SS, k0, wave, lane);
    stage_tile(Bh, Vt, brow0, SS, k0, wave, lane);
    __syncthreads();

    f16x8 ah[4], bh[4];
#pragma unroll
    for (int i = 0; i < 4; ++i) ah[i] = *(const f16x8*)&Ah[(wm + i * 16 + col) * 32 + quad * 8];
#pragma unroll
    for (int j = 0; j < 4; ++j) bh[j] = *(const f16x8*)&Bh[(wn + j * 16 + col) * 32 + quad * 8];
#pragma unroll
    for (int i = 0; i < 4; ++i)
#pragma unroll
      for (int j = 0; j < 4; ++j)
        acc[i][j] = MFMA_F16(ah[i], bh[j], acc[i][j]);
    __syncthreads();
  }

#pragma unroll
  for (int i = 0; i < 4; ++i)
#pragma unroll
    for (int j = 0; j < 4; ++j)
#pragma unroll
      for (int r = 0; r < 4; ++r) {
        const int gm = m0 + wm + i * 16 + quad * 4 + r;
        const int gn = n0 + wn + j * 16 + col;
        out[((size_t)(b0 + bb) * SS + gm) * DD + gn] = acc[i][j][r];
      }
}

// ---------------------------------------------------------------------------
extern "C" void kernel_launch(void* const* d_in, const int* in_sizes, int n_in,
                              void* d_out, int out_size, void* d_ws, size_t ws_size,
                              hipStream_t stream)
{
  const float* t_out = (const float*)d_in[0];
  const float* c_out = (const float*)d_in[1];
  const float* Wq    = (const float*)d_in[2];
  const float* bq    = (const float*)d_in[3];
  const float* Wk    = (const float*)d_in[4];
  const float* bk    = (const float*)d_in[5];
  const float* Wv    = (const float*)d_in[6];
  const float* bv    = (const float*)d_in[7];
  float* out = (float*)d_out;

  // ---- workspace budget ----
  const size_t WELT   = (size_t)DD * DD;
  const size_t SDELT  = (size_t)SS * DD;  // per-batch buffer elems
  const size_t WBYTES = 3 * WELT * sizeof(f16);                       // ~6.3 MB
  const size_t PB     = 7 * SDELT * sizeof(f16)                       // Xh,Xl,Qhi,Qlo,Khi,Vv,Vt
                      + (size_t)SS * SS * sizeof(float);              // Sc
  int c = 1;
  for (int cand : {8, 4, 2}) {
    if (WBYTES + (size_t)cand * PB <= ws_size) { c = cand; break; }
  }

  // ---- layout ----
  char* ws = (char*)d_ws;
  f16* Whq = (f16*)ws;
  f16* Whk = Whq + WELT;
  f16* Whv = Whk + WELT;
  f16* Xh  = Whv + WELT;
  f16* Xl  = Xh  + (size_t)c * SDELT;
  f16* Qhi = Xl  + (size_t)c * SDELT;
  f16* Qlo = Qhi + (size_t)c * SDELT;
  f16* Khi = Qlo + (size_t)c * SDELT;
  f16* Vv  = Khi + (size_t)c * SDELT;
  f16* Vt  = Vv  + (size_t)c * SDELT;
  float* Sc = (float*)(Vt + (size_t)c * SDELT);
  f16* P   = Qhi;  // aliases Qhi+Qlo (dead after qk_gemm); sizes match exactly

  prep_w<<<dim3(1024), dim3(256), 0, stream>>>(Wq, Wk, Wv, Whq, Whk, Whv);

  for (int b0 = 0; b0 < BB; b0 += c) {
    prep_x<<<dim3(c * SS), dim3(256), 0, stream>>>(t_out, c_out, Xh, Xl, b0);
    proj_gemm<<<dim3(8, c * 16, 3), dim3(256), 0, stream>>>(
        Xh, Xl, Whq, Whk, Whv, bq, bk, bv, Qhi, Qlo, Khi, Vv);
    transpose_v<<<dim3(32, 16, c), dim3(256), 0, stream>>>(Vv, Vt);
    qk_gemm<<<dim3(16, 16, c), dim3(256), 0, stream>>>(Qhi, Qlo, Khi, Sc);
    softmax_rows<<<dim3(c * SS), dim3(256), 0, stream>>>(Sc, P);
    pv_gemm<<<dim3(8, 16, c), dim3(256), 0, stream>>>(P, Vt, out, b0);
  }
}

// Round 5
// 556.286 us; speedup vs baseline: 1.6340x; 1.3167x over previous
//
#include <hip/hip_runtime.h>
#include <cstdint>
#include <cstddef>

typedef _Float16 f16;
typedef __attribute__((ext_vector_type(4))) _Float16 f16x4;
typedef __attribute__((ext_vector_type(8))) _Float16 f16x8;
typedef __attribute__((ext_vector_type(4))) float f32x4;

#define MFMA_F16(a, b, c) __builtin_amdgcn_mfma_f32_16x16x32_f16((a), (b), (c), 0, 0, 0)

static constexpr int BB   = 8;
static constexpr int SS   = 2048;
static constexpr int DD   = 1024;
static constexpr int HALF = 512;

// async global->LDS, 16 B per lane; LDS dest is wave-uniform base + lane*16.
__device__ __forceinline__ void gll16(const f16* g, f16* lds) {
  __builtin_amdgcn_global_load_lds(
      (__attribute__((address_space(1))) void*)(g),
      (__attribute__((address_space(3))) void*)(lds), 16, 0, 0);
}

// ---------------------------------------------------------------------------
// Weights -> fp16 (single term; residual terms empirically invisible)
// ---------------------------------------------------------------------------
__global__ __launch_bounds__(256) void prep_w(
    const float* __restrict__ Wq, const float* __restrict__ Wk, const float* __restrict__ Wv,
    f16* __restrict__ Whq, f16* __restrict__ Whk, f16* __restrict__ Whv)
{
  const int i = (blockIdx.x * 256 + threadIdx.x) * 4;
  const float4 q = *(const float4*)(Wq + i);
  const float4 k = *(const float4*)(Wk + i);
  const float4 v = *(const float4*)(Wv + i);
  f16x4 a;
  a.x = (f16)q.x; a.y = (f16)q.y; a.z = (f16)q.z; a.w = (f16)q.w; *(f16x4*)(Whq + i) = a;
  a.x = (f16)k.x; a.y = (f16)k.y; a.z = (f16)k.z; a.w = (f16)k.w; *(f16x4*)(Whk + i) = a;
  a.x = (f16)v.x; a.y = (f16)v.y; a.z = (f16)v.z; a.w = (f16)v.w; *(f16x4*)(Whv + i) = a;
}

// ---------------------------------------------------------------------------
// X = concat(t_out, c_out) for chunk tokens -> fp16
// grid: c*SS blocks of 256, 4 f16 per thread => exactly c*SS*DD elements.
// ---------------------------------------------------------------------------
__global__ __launch_bounds__(256) void prep_x(
    const float* __restrict__ t_out, const float* __restrict__ c_out,
    f16* __restrict__ Xh, int b0)
{
  const size_t i = ((size_t)blockIdx.x * 256 + threadIdx.x) * 4;
  const int d = (int)(i & 1023);
  const size_t g = (size_t)b0 * SS + (i >> 10);
  const float* src = (d < HALF) ? (t_out + g * HALF + d)
                                : (c_out + g * HALF + (d - HALF));
  const float4 x = *(const float4*)src;
  f16x4 h;
  h.x = (f16)x.x; h.y = (f16)x.y; h.z = (f16)x.z; h.w = (f16)x.w;
  *(f16x4*)(Xh + i) = h;
}

// ---------------------------------------------------------------------------
// stage one 128x32-f16 LDS tile (8 KB) from row-major global [row][ld]
// ---------------------------------------------------------------------------
__device__ __forceinline__ void stage_tile(
    f16* lds, const f16* g, size_t row0, int ld, int k0, int wave, int lane)
{
  const int lrow = lane >> 2;          // 0..15
  const int lq8  = (lane & 3) << 3;    // 0,8,16,24 (f16)
#pragma unroll
  for (int r = 0; r < 2; ++r) {
    const int rb = r * 64 + wave * 16;  // wave-uniform
    gll16(g + (row0 + (size_t)(rb + lrow)) * ld + k0 + lq8, lds + rb * 32);
  }
}

// ---------------------------------------------------------------------------
// QKV projection, single MFMA pass per z.  z=0: Q, z=1: K, z=2: V.
// C[m][n] = sum_k Xh[m][k] * Wh[n][k] + bias[n], stored fp16.
// ---------------------------------------------------------------------------
__global__ __launch_bounds__(256) void proj_gemm(
    const f16* __restrict__ Xh,
    const f16* __restrict__ Whq, const f16* __restrict__ Whk, const f16* __restrict__ Whv,
    const float* __restrict__ bq, const float* __restrict__ bk, const float* __restrict__ bv,
    f16* __restrict__ Qhi, f16* __restrict__ Khi, f16* __restrict__ Vv)
{
  __shared__ alignas(16) f16 Ah[128 * 32];
  __shared__ alignas(16) f16 Bh[128 * 32];

  const int z = blockIdx.z;
  const f16* Wh = (z == 0) ? Whq : (z == 1) ? Whk : Whv;
  const float* bias = (z == 0) ? bq : (z == 1) ? bk : bv;
  f16* dst = (z == 0) ? Qhi : (z == 1) ? Khi : Vv;

  const int t    = threadIdx.x;
  const int m0   = blockIdx.y * 128;
  const int n0   = blockIdx.x * 128;
  const int lane = t & 63;
  const int wave = t >> 6;
  const int wm   = (wave & 1) << 6;
  const int wn   = (wave >> 1) << 6;
  const int col  = lane & 15;
  const int quad = lane >> 4;

  f32x4 acc[4][4];
#pragma unroll
  for (int i = 0; i < 4; ++i)
#pragma unroll
    for (int j = 0; j < 4; ++j)
      acc[i][j] = f32x4{0.f, 0.f, 0.f, 0.f};

  for (int k0 = 0; k0 < DD; k0 += 32) {
    stage_tile(Ah, Xh, (size_t)m0, DD, k0, wave, lane);
    stage_tile(Bh, Wh, (size_t)n0, DD, k0, wave, lane);
    __syncthreads();

    f16x8 ah[4], bh[4];
#pragma unroll
    for (int i = 0; i < 4; ++i) ah[i] = *(const f16x8*)&Ah[(wm + i * 16 + col) * 32 + quad * 8];
#pragma unroll
    for (int j = 0; j < 4; ++j) bh[j] = *(const f16x8*)&Bh[(wn + j * 16 + col) * 32 + quad * 8];
#pragma unroll
    for (int i = 0; i < 4; ++i)
#pragma unroll
      for (int j = 0; j < 4; ++j)
        acc[i][j] = MFMA_F16(ah[i], bh[j], acc[i][j]);
    __syncthreads();
  }

  // epilogue: C/D row = quad*4+r (M), col = lane&15 (N)
#pragma unroll
  for (int j = 0; j < 4; ++j) {
    const int gn = n0 + wn + j * 16 + col;
    const float bb = bias[gn];
#pragma unroll
    for (int i = 0; i < 4; ++i) {
#pragma unroll
      for (int r = 0; r < 4; ++r) {
        const int gm = m0 + wm + i * 16 + quad * 4 + r;
        dst[(size_t)gm * DD + gn] = (f16)(acc[i][j][r] + bb);
      }
    }
  }
}

// ---------------------------------------------------------------------------
// Transpose V [bb][s][e] -> Vt [bb][e][s]
// ---------------------------------------------------------------------------
__global__ __launch_bounds__(256) void transpose_v(
    const f16* __restrict__ Vv, f16* __restrict__ Vt)
{
  __shared__ alignas(16) f16 tile[64][72];
  const int bb = blockIdx.z;
  const int s0 = blockIdx.x * 64;
  const int e0 = blockIdx.y * 64;
  const int t  = threadIdx.x;
  const int r  = t >> 3;
  const int c8 = (t & 7) * 8;

  const f16* src0 = Vv + ((size_t)(bb * SS + s0 + r)) * DD + e0 + c8;
  const f16* src1 = Vv + ((size_t)(bb * SS + s0 + r + 32)) * DD + e0 + c8;
  *(int4*)&tile[r][c8]      = *(const int4*)src0;
  *(int4*)&tile[r + 32][c8] = *(const int4*)src1;
  __syncthreads();

  f16x8 v0, v1;
#pragma unroll
  for (int u = 0; u < 8; ++u) {
    v0[u] = tile[c8 + u][r];
    v1[u] = tile[c8 + u][r + 32];
  }
  f16* dst0 = Vt + ((size_t)bb * DD + e0 + r) * SS + s0 + c8;
  f16* dst1 = Vt + ((size_t)bb * DD + e0 + r + 32) * SS + s0 + c8;
  *(f16x8*)dst0 = v0;
  *(f16x8*)dst1 = v1;
}

// ---------------------------------------------------------------------------
// Scores: Sc = qh . kh  (single pass, m97 shape)
// ---------------------------------------------------------------------------
__global__ __launch_bounds__(256) void qk_gemm(
    const f16* __restrict__ Qhi, const f16* __restrict__ Khi, float* __restrict__ Sc)
{
  __shared__ alignas(16) f16 Ah[128 * 32];
  __shared__ alignas(16) f16 Bh[128 * 32];

  const int bb   = blockIdx.z;
  const int t    = threadIdx.x;
  const int m0   = blockIdx.y * 128;
  const int n0   = blockIdx.x * 128;
  const int lane = t & 63;
  const int wave = t >> 6;
  const int wm   = (wave & 1) << 6;
  const int wn   = (wave >> 1) << 6;
  const int col  = lane & 15;
  const int quad = lane >> 4;

  const size_t arow0 = (size_t)(bb * SS + m0);
  const size_t brow0 = (size_t)(bb * SS + n0);

  f32x4 acc[4][4];
#pragma unroll
  for (int i = 0; i < 4; ++i)
#pragma unroll
    for (int j = 0; j < 4; ++j)
      acc[i][j] = f32x4{0.f, 0.f, 0.f, 0.f};

  for (int k0 = 0; k0 < DD; k0 += 32) {
    stage_tile(Ah, Qhi, arow0, DD, k0, wave, lane);
    stage_tile(Bh, Khi, brow0, DD, k0, wave, lane);
    __syncthreads();

    f16x8 ah[4], bh[4];
#pragma unroll
    for (int i = 0; i < 4; ++i) ah[i] = *(const f16x8*)&Ah[(wm + i * 16 + col) * 32 + quad * 8];
#pragma unroll
    for (int j = 0; j < 4; ++j) bh[j] = *(const f16x8*)&Bh[(wn + j * 16 + col) * 32 + quad * 8];
#pragma unroll
    for (int i = 0; i < 4; ++i)
#pragma unroll
      for (int j = 0; j < 4; ++j)
        acc[i][j] = MFMA_F16(ah[i], bh[j], acc[i][j]);
    __syncthreads();
  }

#pragma unroll
  for (int i = 0; i < 4; ++i)
#pragma unroll
    for (int j = 0; j < 4; ++j)
#pragma unroll
      for (int r = 0; r < 4; ++r) {
        const int gm = m0 + wm + i * 16 + quad * 4 + r;
        const int gn = n0 + wn + j * 16 + col;
        Sc[((size_t)bb * SS + gm) * SS + gn] = acc[i][j][r];
      }
}

// ---------------------------------------------------------------------------
// Row softmax fp32 -> normalized fp16 P
// ---------------------------------------------------------------------------
__global__ __launch_bounds__(256) void softmax_rows(
    const float* __restrict__ Sc, f16* __restrict__ P)
{
  const size_t row = blockIdx.x;
  const float* src = Sc + row * SS;
  const int t = threadIdx.x;

  const float4 x0 = *(const float4*)(src + t * 4);
  const float4 x1 = *(const float4*)(src + 1024 + t * 4);
  float xs[8] = {x0.x, x0.y, x0.z, x0.w, x1.x, x1.y, x1.z, x1.w};

  float m = xs[0];
#pragma unroll
  for (int u = 1; u < 8; ++u) m = fmaxf(m, xs[u]);
#pragma unroll
  for (int off = 32; off > 0; off >>= 1) m = fmaxf(m, __shfl_xor(m, off));
  __shared__ float redm[4];
  __shared__ float reds[4];
  if ((t & 63) == 0) redm[t >> 6] = m;
  __syncthreads();
  m = fmaxf(fmaxf(redm[0], redm[1]), fmaxf(redm[2], redm[3]));

  float e[8];
  float s = 0.f;
#pragma unroll
  for (int u = 0; u < 8; ++u) {
    e[u] = expf(xs[u] - m);
    s += e[u];
  }
#pragma unroll
  for (int off = 32; off > 0; off >>= 1) s += __shfl_xor(s, off);
  if ((t & 63) == 0) reds[t >> 6] = s;
  __syncthreads();
  s = reds[0] + reds[1] + reds[2] + reds[3];
  const float inv = 1.0f / s;

  f16x4 o0, o1;
  o0.x = (f16)(e[0] * inv); o0.y = (f16)(e[1] * inv);
  o0.z = (f16)(e[2] * inv); o0.w = (f16)(e[3] * inv);
  o1.x = (f16)(e[4] * inv); o1.y = (f16)(e[5] * inv);
  o1.z = (f16)(e[6] * inv); o1.w = (f16)(e[7] * inv);
  *(f16x4*)(P + row * SS + t * 4)        = o0;
  *(f16x4*)(P + row * SS + 1024 + t * 4) = o1;
}

// ---------------------------------------------------------------------------
// Output: out[b0+bb][s][e] = sum_j P[bb][s][j] * Vt[bb][e][j]
// ---------------------------------------------------------------------------
__global__ __launch_bounds__(256) void pv_gemm(
    const f16* __restrict__ P, const f16* __restrict__ Vt, float* __restrict__ out,
    int b0)
{
  __shared__ alignas(16) f16 Ah[128 * 32];
  __shared__ alignas(16) f16 Bh[128 * 32];

  const int bb   = blockIdx.z;
  const int t    = threadIdx.x;
  const int m0   = blockIdx.y * 128;  // s
  const int n0   = blockIdx.x * 128;  // e
  const int lane = t & 63;
  const int wave = t >> 6;
  const int wm   = (wave & 1) << 6;
  const int wn   = (wave >> 1) << 6;
  const int col  = lane & 15;
  const int quad = lane >> 4;

  const size_t arow0 = (size_t)bb * SS + m0;
  const size_t brow0 = (size_t)bb * DD + n0;

  f32x4 acc[4][4];
#pragma unroll
  for (int i = 0; i < 4; ++i)
#pragma unroll
    for (int j = 0; j < 4; ++j)
      acc[i][j] = f32x4{0.f, 0.f, 0.f, 0.f};

  for (int k0 = 0; k0 < SS; k0 += 32) {
    stage_tile(Ah, P, arow0, SS, k0, wave, lane);
    stage_tile(Bh, Vt, brow0, SS, k0, wave, lane);
    __syncthreads();

    f16x8 ah[4], bh[4];
#pragma unroll
    for (int i = 0; i < 4; ++i) ah[i] = *(const f16x8*)&Ah[(wm + i * 16 + col) * 32 + quad * 8];
#pragma unroll
    for (int j = 0; j < 4; ++j) bh[j] = *(const f16x8*)&Bh[(wn + j * 16 + col) * 32 + quad * 8];
#pragma unroll
    for (int i = 0; i < 4; ++i)
#pragma unroll
      for (int j = 0; j < 4; ++j)
        acc[i][j] = MFMA_F16(ah[i], bh[j], acc[i][j]);
    __syncthreads();
  }

#pragma unroll
  for (int i = 0; i < 4; ++i)
#pragma unroll
    for (int j = 0; j < 4; ++j)
#pragma unroll
      for (int r = 0; r < 4; ++r) {
        const int gm = m0 + wm + i * 16 + quad * 4 + r;
        const int gn = n0 + wn + j * 16 + col;
        out[((size_t)(b0 + bb) * SS + gm) * DD + gn] = acc[i][j][r];
      }
}

// ---------------------------------------------------------------------------
extern "C" void kernel_launch(void* const* d_in, const int* in_sizes, int n_in,
                              void* d_out, int out_size, void* d_ws, size_t ws_size,
                              hipStream_t stream)
{
  const float* t_out = (const float*)d_in[0];
  const float* c_out = (const float*)d_in[1];
  const float* Wq    = (const float*)d_in[2];
  const float* bq    = (const float*)d_in[3];
  const float* Wk    = (const float*)d_in[4];
  const float* bk    = (const float*)d_in[5];
  const float* Wv    = (const float*)d_in[6];
  const float* bv    = (const float*)d_in[7];
  float* out = (float*)d_out;

  // ---- workspace budget ----
  const size_t WELT   = (size_t)DD * DD;
  const size_t SDELT  = (size_t)SS * DD;                 // per-batch buffer elems
  const size_t WBYTES = 3 * WELT * sizeof(f16);          // ~6.3 MB
  const size_t PB     = 5 * SDELT * sizeof(f16)          // Xh,Qhi,Khi,Vv,Vt
                      + (size_t)SS * SS * sizeof(float); // Sc: 36 MB/batch total
  int c = 1;
  for (int cand : {8, 4, 2}) {
    if (WBYTES + (size_t)cand * PB <= ws_size) { c = cand; break; }
  }

  // ---- layout (Qhi and Khi adjacent: P aliases their union, exact size) ----
  char* ws = (char*)d_ws;
  f16* Whq = (f16*)ws;
  f16* Whk = Whq + WELT;
  f16* Whv = Whk + WELT;
  f16* Xh  = Whv + WELT;
  f16* Qhi = Xh  + (size_t)c * SDELT;
  f16* Khi = Qhi + (size_t)c * SDELT;
  f16* Vv  = Khi + (size_t)c * SDELT;
  f16* Vt  = Vv  + (size_t)c * SDELT;
  float* Sc = (float*)(Vt + (size_t)c * SDELT);
  f16* P   = Qhi;  // c*S*S f16 = c*8MB = Qhi(4MB*c)+Khi(4MB*c); dead after qk

  prep_w<<<dim3(1024), dim3(256), 0, stream>>>(Wq, Wk, Wv, Whq, Whk, Whv);

  for (int b0 = 0; b0 < BB; b0 += c) {
    prep_x<<<dim3(c * SS), dim3(256), 0, stream>>>(t_out, c_out, Xh, b0);
    proj_gemm<<<dim3(8, c * 16, 3), dim3(256), 0, stream>>>(
        Xh, Whq, Whk, Whv, bq, bk, bv, Qhi, Khi, Vv);
    transpose_v<<<dim3(32, 16, c), dim3(256), 0, stream>>>(Vv, Vt);
    qk_gemm<<<dim3(16, 16, c), dim3(256), 0, stream>>>(Qhi, Khi, Sc);
    softmax_rows<<<dim3(c * SS), dim3(256), 0, stream>>>(Sc, P);
    pv_gemm<<<dim3(8, 16, c), dim3(256), 0, stream>>>(P, Vt, out, b0);
  }
}

// Round 6
// 553.134 us; speedup vs baseline: 1.6433x; 1.0057x over previous
//
#include <hip/hip_runtime.h>
#include <cstdint>
#include <cstddef>

typedef _Float16 f16;
typedef __attribute__((ext_vector_type(4))) _Float16 f16x4;
typedef __attribute__((ext_vector_type(8))) _Float16 f16x8;
typedef __attribute__((ext_vector_type(4))) float f32x4;

#define MFMA_F16(a, b, c) __builtin_amdgcn_mfma_f32_16x16x32_f16((a), (b), (c), 0, 0, 0)

static constexpr int BB   = 8;
static constexpr int SS   = 2048;
static constexpr int DD   = 1024;
static constexpr int HALF = 512;

// async global->LDS, 16 B per lane; LDS dest is wave-uniform base + lane*16.
__device__ __forceinline__ void gll16(const f16* g, f16* lds) {
  __builtin_amdgcn_global_load_lds(
      (__attribute__((address_space(1))) void*)(g),
      (__attribute__((address_space(3))) void*)(lds), 16, 0, 0);
}

// ---------------------------------------------------------------------------
// Fused prep: blocks [0,1024) convert W (fp32->fp16); blocks [1024,1024+16384)
// build Xh = concat(t_out,c_out) fp16 for ALL 8 batches.
// ---------------------------------------------------------------------------
__global__ __launch_bounds__(256) void fused_prep(
    const float* __restrict__ Wq, const float* __restrict__ Wk, const float* __restrict__ Wv,
    const float* __restrict__ t_out, const float* __restrict__ c_out,
    f16* __restrict__ Whq, f16* __restrict__ Whk, f16* __restrict__ Whv,
    f16* __restrict__ Xh)
{
  if (blockIdx.x < 1024) {
    const int i = (blockIdx.x * 256 + threadIdx.x) * 4;
    const float4 q = *(const float4*)(Wq + i);
    const float4 k = *(const float4*)(Wk + i);
    const float4 v = *(const float4*)(Wv + i);
    f16x4 a;
    a.x = (f16)q.x; a.y = (f16)q.y; a.z = (f16)q.z; a.w = (f16)q.w; *(f16x4*)(Whq + i) = a;
    a.x = (f16)k.x; a.y = (f16)k.y; a.z = (f16)k.z; a.w = (f16)k.w; *(f16x4*)(Whk + i) = a;
    a.x = (f16)v.x; a.y = (f16)v.y; a.z = (f16)v.z; a.w = (f16)v.w; *(f16x4*)(Whv + i) = a;
  } else {
    const size_t i = ((size_t)(blockIdx.x - 1024) * 256 + threadIdx.x) * 4;
    const int d = (int)(i & 1023);
    const size_t g = i >> 10;  // global token 0..16383
    const float* src = (d < HALF) ? (t_out + g * HALF + d)
                                  : (c_out + g * HALF + (d - HALF));
    const float4 x = *(const float4*)src;
    f16x4 h;
    h.x = (f16)x.x; h.y = (f16)x.y; h.z = (f16)x.z; h.w = (f16)x.w;
    *(f16x4*)(Xh + i) = h;
  }
}

// ---------------------------------------------------------------------------
// stage one 128x32-f16 LDS tile (8 KB) from row-major global [row][ld]
// ---------------------------------------------------------------------------
__device__ __forceinline__ void stage_tile(
    f16* lds, const f16* g, size_t row0, int ld, int k0, int wave, int lane)
{
  const int lrow = lane >> 2;          // 0..15
  const int lq8  = (lane & 3) << 3;    // 0,8,16,24 (f16)
#pragma unroll
  for (int r = 0; r < 2; ++r) {
    const int rb = r * 64 + wave * 16;  // wave-uniform
    gll16(g + (row0 + (size_t)(rb + lrow)) * ld + k0 + lq8, lds + rb * 32);
  }
}

// ---------------------------------------------------------------------------
// QKV projection, full batch, single MFMA pass. z=0: Q, z=1: K, z=2: V.
// C[m][n] = sum_k Xh[m][k] * Wh[n][k] + bias[n], stored fp16.
// grid (8, 128, 3): m covers all 16384 tokens.
// ---------------------------------------------------------------------------
__global__ __launch_bounds__(256) void proj_gemm(
    const f16* __restrict__ Xh,
    const f16* __restrict__ Whq, const f16* __restrict__ Whk, const f16* __restrict__ Whv,
    const float* __restrict__ bq, const float* __restrict__ bk, const float* __restrict__ bv,
    f16* __restrict__ Q, f16* __restrict__ K, f16* __restrict__ Vv)
{
  __shared__ alignas(16) f16 Ah[128 * 32];
  __shared__ alignas(16) f16 Bh[128 * 32];

  const int z = blockIdx.z;
  const f16* Wh = (z == 0) ? Whq : (z == 1) ? Whk : Whv;
  const float* bias = (z == 0) ? bq : (z == 1) ? bk : bv;
  f16* dst = (z == 0) ? Q : (z == 1) ? K : Vv;

  const int t    = threadIdx.x;
  const int m0   = blockIdx.y * 128;
  const int n0   = blockIdx.x * 128;
  const int lane = t & 63;
  const int wave = t >> 6;
  const int wm   = (wave & 1) << 6;
  const int wn   = (wave >> 1) << 6;
  const int col  = lane & 15;
  const int quad = lane >> 4;

  f32x4 acc[4][4];
#pragma unroll
  for (int i = 0; i < 4; ++i)
#pragma unroll
    for (int j = 0; j < 4; ++j)
      acc[i][j] = f32x4{0.f, 0.f, 0.f, 0.f};

  for (int k0 = 0; k0 < DD; k0 += 32) {
    stage_tile(Ah, Xh, (size_t)m0, DD, k0, wave, lane);
    stage_tile(Bh, Wh, (size_t)n0, DD, k0, wave, lane);
    __syncthreads();

    f16x8 ah[4], bh[4];
#pragma unroll
    for (int i = 0; i < 4; ++i) ah[i] = *(const f16x8*)&Ah[(wm + i * 16 + col) * 32 + quad * 8];
#pragma unroll
    for (int j = 0; j < 4; ++j) bh[j] = *(const f16x8*)&Bh[(wn + j * 16 + col) * 32 + quad * 8];
#pragma unroll
    for (int i = 0; i < 4; ++i)
#pragma unroll
      for (int j = 0; j < 4; ++j)
        acc[i][j] = MFMA_F16(ah[i], bh[j], acc[i][j]);
    __syncthreads();
  }

  // epilogue: C/D row = quad*4+r (M), col = lane&15 (N)
#pragma unroll
  for (int j = 0; j < 4; ++j) {
    const int gn = n0 + wn + j * 16 + col;
    const float bb = bias[gn];
#pragma unroll
    for (int i = 0; i < 4; ++i) {
#pragma unroll
      for (int r = 0; r < 4; ++r) {
        const int gm = m0 + wm + i * 16 + quad * 4 + r;
        dst[(size_t)gm * DD + gn] = (f16)(acc[i][j][r] + bb);
      }
    }
  }
}

// ---------------------------------------------------------------------------
// Transpose V [b][s][e] -> Vt [b][e][s], full batch (grid 32,16,8)
// ---------------------------------------------------------------------------
__global__ __launch_bounds__(256) void transpose_v(
    const f16* __restrict__ Vv, f16* __restrict__ Vt)
{
  __shared__ alignas(16) f16 tile[64][72];
  const int b  = blockIdx.z;
  const int s0 = blockIdx.x * 64;
  const int e0 = blockIdx.y * 64;
  const int t  = threadIdx.x;
  const int r  = t >> 3;
  const int c8 = (t & 7) * 8;

  const f16* src0 = Vv + ((size_t)(b * SS + s0 + r)) * DD + e0 + c8;
  const f16* src1 = Vv + ((size_t)(b * SS + s0 + r + 32)) * DD + e0 + c8;
  *(int4*)&tile[r][c8]      = *(const int4*)src0;
  *(int4*)&tile[r + 32][c8] = *(const int4*)src1;
  __syncthreads();

  f16x8 v0, v1;
#pragma unroll
  for (int u = 0; u < 8; ++u) {
    v0[u] = tile[c8 + u][r];
    v1[u] = tile[c8 + u][r + 32];
  }
  f16* dst0 = Vt + ((size_t)b * DD + e0 + r) * SS + s0 + c8;
  f16* dst1 = Vt + ((size_t)b * DD + e0 + r + 32) * SS + s0 + c8;
  *(f16x8*)dst0 = v0;
  *(f16x8*)dst1 = v1;
}

// ---------------------------------------------------------------------------
// Scores for chunk [b0, b0+c): Sc[bb][i][j] = sum_d Q[(b0+bb)S+i][d]*K[..j][d]
// ---------------------------------------------------------------------------
__global__ __launch_bounds__(256) void qk_gemm(
    const f16* __restrict__ Q, const f16* __restrict__ K, float* __restrict__ Sc,
    int b0)
{
  __shared__ alignas(16) f16 Ah[128 * 32];
  __shared__ alignas(16) f16 Bh[128 * 32];

  const int bb   = blockIdx.z;
  const int t    = threadIdx.x;
  const int m0   = blockIdx.y * 128;
  const int n0   = blockIdx.x * 128;
  const int lane = t & 63;
  const int wave = t >> 6;
  const int wm   = (wave & 1) << 6;
  const int wn   = (wave >> 1) << 6;
  const int col  = lane & 15;
  const int quad = lane >> 4;

  const size_t arow0 = (size_t)(b0 + bb) * SS + m0;
  const size_t brow0 = (size_t)(b0 + bb) * SS + n0;

  f32x4 acc[4][4];
#pragma unroll
  for (int i = 0; i < 4; ++i)
#pragma unroll
    for (int j = 0; j < 4; ++j)
      acc[i][j] = f32x4{0.f, 0.f, 0.f, 0.f};

  for (int k0 = 0; k0 < DD; k0 += 32) {
    stage_tile(Ah, Q, arow0, DD, k0, wave, lane);
    stage_tile(Bh, K, brow0, DD, k0, wave, lane);
    __syncthreads();

    f16x8 ah[4], bh[4];
#pragma unroll
    for (int i = 0; i < 4; ++i) ah[i] = *(const f16x8*)&Ah[(wm + i * 16 + col) * 32 + quad * 8];
#pragma unroll
    for (int j = 0; j < 4; ++j) bh[j] = *(const f16x8*)&Bh[(wn + j * 16 + col) * 32 + quad * 8];
#pragma unroll
    for (int i = 0; i < 4; ++i)
#pragma unroll
      for (int j = 0; j < 4; ++j)
        acc[i][j] = MFMA_F16(ah[i], bh[j], acc[i][j]);
    __syncthreads();
  }

#pragma unroll
  for (int i = 0; i < 4; ++i)
#pragma unroll
    for (int j = 0; j < 4; ++j)
#pragma unroll
      for (int r = 0; r < 4; ++r) {
        const int gm = m0 + wm + i * 16 + quad * 4 + r;
        const int gn = n0 + wn + j * 16 + col;
        Sc[((size_t)bb * SS + gm) * SS + gn] = acc[i][j][r];
      }
}

// ---------------------------------------------------------------------------
// Row softmax fp32 -> fp16 P written IN PLACE into the row's own storage
// (P row = first 2048 f16 of the row's 2048-float span; pitch 2*SS f16).
// Safe: all global reads precede first __syncthreads, writes follow last one.
// ---------------------------------------------------------------------------
__global__ __launch_bounds__(256) void softmax_rows(
    float* __restrict__ Sc)
{
  const size_t row = blockIdx.x;
  const float* src = Sc + row * SS;
  f16* dst = (f16*)(Sc + row * SS);  // in-place, fp16 over first half of span
  const int t = threadIdx.x;

  const float4 x0 = *(const float4*)(src + t * 4);
  const float4 x1 = *(const float4*)(src + 1024 + t * 4);
  float xs[8] = {x0.x, x0.y, x0.z, x0.w, x1.x, x1.y, x1.z, x1.w};

  float m = xs[0];
#pragma unroll
  for (int u = 1; u < 8; ++u) m = fmaxf(m, xs[u]);
#pragma unroll
  for (int off = 32; off > 0; off >>= 1) m = fmaxf(m, __shfl_xor(m, off));
  __shared__ float redm[4];
  __shared__ float reds[4];
  if ((t & 63) == 0) redm[t >> 6] = m;
  __syncthreads();
  m = fmaxf(fmaxf(redm[0], redm[1]), fmaxf(redm[2], redm[3]));

  float e[8];
  float s = 0.f;
#pragma unroll
  for (int u = 0; u < 8; ++u) {
    e[u] = expf(xs[u] - m);
    s += e[u];
  }
#pragma unroll
  for (int off = 32; off > 0; off >>= 1) s += __shfl_xor(s, off);
  if ((t & 63) == 0) reds[t >> 6] = s;
  __syncthreads();
  s = reds[0] + reds[1] + reds[2] + reds[3];
  const float inv = 1.0f / s;

  f16x4 o0, o1;
  o0.x = (f16)(e[0] * inv); o0.y = (f16)(e[1] * inv);
  o0.z = (f16)(e[2] * inv); o0.w = (f16)(e[3] * inv);
  o1.x = (f16)(e[4] * inv); o1.y = (f16)(e[5] * inv);
  o1.z = (f16)(e[6] * inv); o1.w = (f16)(e[7] * inv);
  *(f16x4*)(dst + t * 4)        = o0;
  *(f16x4*)(dst + 1024 + t * 4) = o1;
}

// ---------------------------------------------------------------------------
// Output: out[(b0+bb)][s][e] = sum_j P[bb][s][j] * Vt[b0+bb][e][j]
// P lives in Sc with row pitch 2*SS f16.
// ---------------------------------------------------------------------------
__global__ __launch_bounds__(256) void pv_gemm(
    const f16* __restrict__ P, const f16* __restrict__ Vt, float* __restrict__ out,
    int b0)
{
  __shared__ alignas(16) f16 Ah[128 * 32];
  __shared__ alignas(16) f16 Bh[128 * 32];

  const int bb   = blockIdx.z;
  const int t    = threadIdx.x;
  const int m0   = blockIdx.y * 128;  // s
  const int n0   = blockIdx.x * 128;  // e
  const int lane = t & 63;
  const int wave = t >> 6;
  const int wm   = (wave & 1) << 6;
  const int wn   = (wave >> 1) << 6;
  const int col  = lane & 15;
  const int quad = lane >> 4;

  const size_t arow0 = (size_t)bb * SS + m0;            // P rows (pitch 2*SS)
  const size_t brow0 = (size_t)(b0 + bb) * DD + n0;     // Vt rows (pitch SS)

  f32x4 acc[4][4];
#pragma unroll
  for (int i = 0; i < 4; ++i)
#pragma unroll
    for (int j = 0; j < 4; ++j)
      acc[i][j] = f32x4{0.f, 0.f, 0.f, 0.f};

  for (int k0 = 0; k0 < SS; k0 += 32) {
    stage_tile(Ah, P, arow0, 2 * SS, k0, wave, lane);
    stage_tile(Bh, Vt, brow0, SS, k0, wave, lane);
    __syncthreads();

    f16x8 ah[4], bh[4];
#pragma unroll
    for (int i = 0; i < 4; ++i) ah[i] = *(const f16x8*)&Ah[(wm + i * 16 + col) * 32 + quad * 8];
#pragma unroll
    for (int j = 0; j < 4; ++j) bh[j] = *(const f16x8*)&Bh[(wn + j * 16 + col) * 32 + quad * 8];
#pragma unroll
    for (int i = 0; i < 4; ++i)
#pragma unroll
      for (int j = 0; j < 4; ++j)
        acc[i][j] = MFMA_F16(ah[i], bh[j], acc[i][j]);
    __syncthreads();
  }

#pragma unroll
  for (int i = 0; i < 4; ++i)
#pragma unroll
    for (int j = 0; j < 4; ++j)
#pragma unroll
      for (int r = 0; r < 4; ++r) {
        const int gm = m0 + wm + i * 16 + quad * 4 + r;
        const int gn = n0 + wn + j * 16 + col;
        out[((size_t)(b0 + bb) * SS + gm) * DD + gn] = acc[i][j][r];
      }
}

// ---------------------------------------------------------------------------
extern "C" void kernel_launch(void* const* d_in, const int* in_sizes, int n_in,
                              void* d_out, int out_size, void* d_ws, size_t ws_size,
                              hipStream_t stream)
{
  const float* t_out = (const float*)d_in[0];
  const float* c_out = (const float*)d_in[1];
  const float* Wq    = (const float*)d_in[2];
  const float* bq    = (const float*)d_in[3];
  const float* Wk    = (const float*)d_in[4];
  const float* bk    = (const float*)d_in[5];
  const float* Wv    = (const float*)d_in[6];
  const float* bv    = (const float*)d_in[7];
  float* out = (float*)d_out;

  // ---- sizes ----
  const size_t WELT  = (size_t)DD * DD;        // weight elems
  const size_t TD8   = (size_t)BB * SS * DD;   // full-batch token*dim elems (16.7M)
  const size_t XH_B  = TD8 * sizeof(f16);      // 33.55 MB
  const size_t SC1_B = (size_t)SS * SS * sizeof(float);  // 16.78 MB per batch

  // ---- pick Sc chunk (graph-safe: function of ws_size only) ----
  // total = W(6.29MB) + max(Xh, c*Sc1) + 4*33.55MB(Q,K,Vv,Vt)
  const size_t FIXED = 3 * WELT * sizeof(f16) + 4 * XH_B;
  int c = 2;
  for (int cand : {8, 4}) {
    size_t xsc = (size_t)cand * SC1_B;
    if (xsc < XH_B) xsc = XH_B;
    if (FIXED + xsc <= ws_size) { c = cand; break; }
  }
  size_t xsc_bytes = (size_t)c * SC1_B;
  if (xsc_bytes < XH_B) xsc_bytes = XH_B;

  // ---- layout ----
  char* ws = (char*)d_ws;
  f16* Whq = (f16*)ws;
  f16* Whk = Whq + WELT;
  f16* Whv = Whk + WELT;
  char* XSc = (char*)(Whv + WELT);
  f16*   Xh = (f16*)XSc;       // live during prep/proj
  float* Sc = (float*)XSc;     // live during attention chunks (aliases Xh)
  f16* Q  = (f16*)(XSc + xsc_bytes);
  f16* K  = Q  + TD8;
  f16* Vv = K  + TD8;
  f16* Vt = Vv + TD8;

  fused_prep<<<dim3(1024 + 16384), dim3(256), 0, stream>>>(
      Wq, Wk, Wv, t_out, c_out, Whq, Whk, Whv, Xh);
  proj_gemm<<<dim3(8, 128, 3), dim3(256), 0, stream>>>(
      Xh, Whq, Whk, Whv, bq, bk, bv, Q, K, Vv);
  transpose_v<<<dim3(32, 16, 8), dim3(256), 0, stream>>>(Vv, Vt);

  for (int b0 = 0; b0 < BB; b0 += c) {
    qk_gemm<<<dim3(16, 16, c), dim3(256), 0, stream>>>(Q, K, Sc, b0);
    softmax_rows<<<dim3(c * SS), dim3(256), 0, stream>>>(Sc);
    pv_gemm<<<dim3(8, 16, c), dim3(256), 0, stream>>>((const f16*)Sc, Vt, out, b0);
  }
}

// Round 7
// 510.015 us; speedup vs baseline: 1.7823x; 1.0845x over previous
//
#include <hip/hip_runtime.h>
#include <cstdint>
#include <cstddef>

typedef _Float16 f16;
typedef __attribute__((ext_vector_type(4))) _Float16 f16x4;
typedef __attribute__((ext_vector_type(8))) _Float16 f16x8;
typedef __attribute__((ext_vector_type(4))) float f32x4;

#define MFMA_F16(a, b, c) __builtin_amdgcn_mfma_f32_16x16x32_f16((a), (b), (c), 0, 0, 0)

static constexpr int BB   = 8;
static constexpr int SS   = 2048;
static constexpr int DD   = 1024;
static constexpr int HALF = 512;

// async global->LDS, 16 B per lane; LDS dest is wave-uniform base + lane*16.
__device__ __forceinline__ void gll16(const f16* g, f16* lds) {
  __builtin_amdgcn_global_load_lds(
      (__attribute__((address_space(1))) void*)(g),
      (__attribute__((address_space(3))) void*)(lds), 16, 0, 0);
}

// ---------------------------------------------------------------------------
// Fused prep: blocks [0,1024) convert W (fp32->fp16); blocks [1024,1024+16384)
// build Xh = concat(t_out,c_out) fp16 for ALL 8 batches.
// ---------------------------------------------------------------------------
__global__ __launch_bounds__(256) void fused_prep(
    const float* __restrict__ Wq, const float* __restrict__ Wk, const float* __restrict__ Wv,
    const float* __restrict__ t_out, const float* __restrict__ c_out,
    f16* __restrict__ Whq, f16* __restrict__ Whk, f16* __restrict__ Whv,
    f16* __restrict__ Xh)
{
  if (blockIdx.x < 1024) {
    const int i = (blockIdx.x * 256 + threadIdx.x) * 4;
    const float4 q = *(const float4*)(Wq + i);
    const float4 k = *(const float4*)(Wk + i);
    const float4 v = *(const float4*)(Wv + i);
    f16x4 a;
    a.x = (f16)q.x; a.y = (f16)q.y; a.z = (f16)q.z; a.w = (f16)q.w; *(f16x4*)(Whq + i) = a;
    a.x = (f16)k.x; a.y = (f16)k.y; a.z = (f16)k.z; a.w = (f16)k.w; *(f16x4*)(Whk + i) = a;
    a.x = (f16)v.x; a.y = (f16)v.y; a.z = (f16)v.z; a.w = (f16)v.w; *(f16x4*)(Whv + i) = a;
  } else {
    const size_t i = ((size_t)(blockIdx.x - 1024) * 256 + threadIdx.x) * 4;
    const int d = (int)(i & 1023);
    const size_t g = i >> 10;  // global token 0..16383
    const float* src = (d < HALF) ? (t_out + g * HALF + d)
                                  : (c_out + g * HALF + (d - HALF));
    const float4 x = *(const float4*)src;
    f16x4 h;
    h.x = (f16)x.x; h.y = (f16)x.y; h.z = (f16)x.z; h.w = (f16)x.w;
    *(f16x4*)(Xh + i) = h;
  }
}

// ---------------------------------------------------------------------------
// stage one 128x32-f16 LDS tile (8 KB) from row-major global [row][ld]
// ---------------------------------------------------------------------------
__device__ __forceinline__ void stage_tile(
    f16* lds, const f16* g, size_t row0, int ld, int k0, int wave, int lane)
{
  const int lrow = lane >> 2;          // 0..15
  const int lq8  = (lane & 3) << 3;    // 0,8,16,24 (f16)
#pragma unroll
  for (int r = 0; r < 2; ++r) {
    const int rb = r * 64 + wave * 16;  // wave-uniform
    gll16(g + (row0 + (size_t)(rb + lrow)) * ld + k0 + lq8, lds + rb * 32);
  }
}

// ---------------------------------------------------------------------------
// QKV projection, full batch, single MFMA pass. z=0: Q, z=1: K, z=2: V.
// grid (128, 8, 3): x = m-tile so consecutive blocks share the tiny B tile
// and stream disjoint A tiles (L2/L3 locality for Xh).
// ---------------------------------------------------------------------------
__global__ __launch_bounds__(256) void proj_gemm(
    const f16* __restrict__ Xh,
    const f16* __restrict__ Whq, const f16* __restrict__ Whk, const f16* __restrict__ Whv,
    const float* __restrict__ bq, const float* __restrict__ bk, const float* __restrict__ bv,
    f16* __restrict__ Q, f16* __restrict__ K, f16* __restrict__ Vv)
{
  __shared__ alignas(16) f16 Ah[128 * 32];
  __shared__ alignas(16) f16 Bh[128 * 32];

  const int z = blockIdx.z;
  const f16* Wh = (z == 0) ? Whq : (z == 1) ? Whk : Whv;
  const float* bias = (z == 0) ? bq : (z == 1) ? bk : bv;
  f16* dst = (z == 0) ? Q : (z == 1) ? K : Vv;

  const int t    = threadIdx.x;
  const int m0   = blockIdx.x * 128;   // token rows (swapped: x = m)
  const int n0   = blockIdx.y * 128;
  const int lane = t & 63;
  const int wave = t >> 6;
  const int wm   = (wave & 1) << 6;
  const int wn   = (wave >> 1) << 6;
  const int col  = lane & 15;
  const int quad = lane >> 4;

  f32x4 acc[4][4];
#pragma unroll
  for (int i = 0; i < 4; ++i)
#pragma unroll
    for (int j = 0; j < 4; ++j)
      acc[i][j] = f32x4{0.f, 0.f, 0.f, 0.f};

  for (int k0 = 0; k0 < DD; k0 += 32) {
    stage_tile(Ah, Xh, (size_t)m0, DD, k0, wave, lane);
    stage_tile(Bh, Wh, (size_t)n0, DD, k0, wave, lane);
    __syncthreads();

    f16x8 ah[4], bh[4];
#pragma unroll
    for (int i = 0; i < 4; ++i) ah[i] = *(const f16x8*)&Ah[(wm + i * 16 + col) * 32 + quad * 8];
#pragma unroll
    for (int j = 0; j < 4; ++j) bh[j] = *(const f16x8*)&Bh[(wn + j * 16 + col) * 32 + quad * 8];
#pragma unroll
    for (int i = 0; i < 4; ++i)
#pragma unroll
      for (int j = 0; j < 4; ++j)
        acc[i][j] = MFMA_F16(ah[i], bh[j], acc[i][j]);
    __syncthreads();
  }

  // epilogue: C/D row = quad*4+r (M), col = lane&15 (N)
#pragma unroll
  for (int j = 0; j < 4; ++j) {
    const int gn = n0 + wn + j * 16 + col;
    const float bb = bias[gn];
#pragma unroll
    for (int i = 0; i < 4; ++i) {
#pragma unroll
      for (int r = 0; r < 4; ++r) {
        const int gm = m0 + wm + i * 16 + quad * 4 + r;
        dst[(size_t)gm * DD + gn] = (f16)(acc[i][j][r] + bb);
      }
    }
  }
}

// ---------------------------------------------------------------------------
// Transpose V [b][s][e] -> Vt [b][e][s], full batch (grid 32,16,8)
// ---------------------------------------------------------------------------
__global__ __launch_bounds__(256) void transpose_v(
    const f16* __restrict__ Vv, f16* __restrict__ Vt)
{
  __shared__ alignas(16) f16 tile[64][72];
  const int b  = blockIdx.z;
  const int s0 = blockIdx.x * 64;
  const int e0 = blockIdx.y * 64;
  const int t  = threadIdx.x;
  const int r  = t >> 3;
  const int c8 = (t & 7) * 8;

  const f16* src0 = Vv + ((size_t)(b * SS + s0 + r)) * DD + e0 + c8;
  const f16* src1 = Vv + ((size_t)(b * SS + s0 + r + 32)) * DD + e0 + c8;
  *(int4*)&tile[r][c8]      = *(const int4*)src0;
  *(int4*)&tile[r + 32][c8] = *(const int4*)src1;
  __syncthreads();

  f16x8 v0, v1;
#pragma unroll
  for (int u = 0; u < 8; ++u) {
    v0[u] = tile[c8 + u][r];
    v1[u] = tile[c8 + u][r + 32];
  }
  f16* dst0 = Vt + ((size_t)b * DD + e0 + r) * SS + s0 + c8;
  f16* dst1 = Vt + ((size_t)b * DD + e0 + r + 32) * SS + s0 + c8;
  *(f16x8*)dst0 = v0;
  *(f16x8*)dst1 = v1;
}

// ---------------------------------------------------------------------------
// Scores for chunk [b0, b0+c), fp16 out (logits |x|<~50 fit fp16 comfortably)
// ---------------------------------------------------------------------------
__global__ __launch_bounds__(256) void qk_gemm(
    const f16* __restrict__ Q, const f16* __restrict__ K, f16* __restrict__ Sc,
    int b0)
{
  __shared__ alignas(16) f16 Ah[128 * 32];
  __shared__ alignas(16) f16 Bh[128 * 32];

  const int bb   = blockIdx.z;
  const int t    = threadIdx.x;
  const int m0   = blockIdx.y * 128;
  const int n0   = blockIdx.x * 128;
  const int lane = t & 63;
  const int wave = t >> 6;
  const int wm   = (wave & 1) << 6;
  const int wn   = (wave >> 1) << 6;
  const int col  = lane & 15;
  const int quad = lane >> 4;

  const size_t arow0 = (size_t)(b0 + bb) * SS + m0;
  const size_t brow0 = (size_t)(b0 + bb) * SS + n0;

  f32x4 acc[4][4];
#pragma unroll
  for (int i = 0; i < 4; ++i)
#pragma unroll
    for (int j = 0; j < 4; ++j)
      acc[i][j] = f32x4{0.f, 0.f, 0.f, 0.f};

  for (int k0 = 0; k0 < DD; k0 += 32) {
    stage_tile(Ah, Q, arow0, DD, k0, wave, lane);
    stage_tile(Bh, K, brow0, DD, k0, wave, lane);
    __syncthreads();

    f16x8 ah[4], bh[4];
#pragma unroll
    for (int i = 0; i < 4; ++i) ah[i] = *(const f16x8*)&Ah[(wm + i * 16 + col) * 32 + quad * 8];
#pragma unroll
    for (int j = 0; j < 4; ++j) bh[j] = *(const f16x8*)&Bh[(wn + j * 16 + col) * 32 + quad * 8];
#pragma unroll
    for (int i = 0; i < 4; ++i)
#pragma unroll
      for (int j = 0; j < 4; ++j)
        acc[i][j] = MFMA_F16(ah[i], bh[j], acc[i][j]);
    __syncthreads();
  }

#pragma unroll
  for (int i = 0; i < 4; ++i)
#pragma unroll
    for (int j = 0; j < 4; ++j)
#pragma unroll
      for (int r = 0; r < 4; ++r) {
        const int gm = m0 + wm + i * 16 + quad * 4 + r;
        const int gn = n0 + wn + j * 16 + col;
        Sc[((size_t)bb * SS + gm) * SS + gn] = (f16)acc[i][j][r];
      }
}

// ---------------------------------------------------------------------------
// Row softmax fp16 -> fp16, in place (row = 2048 f16; 256 thr x f16x8).
// All reads complete before first barrier; writes after last -> safe.
// ---------------------------------------------------------------------------
__global__ __launch_bounds__(256) void softmax_rows(f16* __restrict__ Sc)
{
  const size_t row = blockIdx.x;
  f16* p = Sc + row * SS;
  const int t = threadIdx.x;

  const f16x8 v = *(const f16x8*)(p + t * 8);
  float xs[8];
#pragma unroll
  for (int u = 0; u < 8; ++u) xs[u] = (float)v[u];

  float m = xs[0];
#pragma unroll
  for (int u = 1; u < 8; ++u) m = fmaxf(m, xs[u]);
#pragma unroll
  for (int off = 32; off > 0; off >>= 1) m = fmaxf(m, __shfl_xor(m, off));
  __shared__ float redm[4];
  __shared__ float reds[4];
  if ((t & 63) == 0) redm[t >> 6] = m;
  __syncthreads();
  m = fmaxf(fmaxf(redm[0], redm[1]), fmaxf(redm[2], redm[3]));

  float e[8];
  float s = 0.f;
#pragma unroll
  for (int u = 0; u < 8; ++u) {
    e[u] = expf(xs[u] - m);
    s += e[u];
  }
#pragma unroll
  for (int off = 32; off > 0; off >>= 1) s += __shfl_xor(s, off);
  if ((t & 63) == 0) reds[t >> 6] = s;
  __syncthreads();
  s = reds[0] + reds[1] + reds[2] + reds[3];
  const float inv = 1.0f / s;

  f16x8 o;
#pragma unroll
  for (int u = 0; u < 8; ++u) o[u] = (f16)(e[u] * inv);
  *(f16x8*)(p + t * 8) = o;
}

// ---------------------------------------------------------------------------
// Output: out[(b0+bb)][s][e] = sum_j P[bb][s][j] * Vt[b0+bb][e][j]
// P = Sc (fp16, contiguous pitch SS).
// ---------------------------------------------------------------------------
__global__ __launch_bounds__(256) void pv_gemm(
    const f16* __restrict__ P, const f16* __restrict__ Vt, float* __restrict__ out,
    int b0)
{
  __shared__ alignas(16) f16 Ah[128 * 32];
  __shared__ alignas(16) f16 Bh[128 * 32];

  const int bb   = blockIdx.z;
  const int t    = threadIdx.x;
  const int m0   = blockIdx.y * 128;  // s
  const int n0   = blockIdx.x * 128;  // e
  const int lane = t & 63;
  const int wave = t >> 6;
  const int wm   = (wave & 1) << 6;
  const int wn   = (wave >> 1) << 6;
  const int col  = lane & 15;
  const int quad = lane >> 4;

  const size_t arow0 = (size_t)bb * SS + m0;            // P rows (pitch SS)
  const size_t brow0 = (size_t)(b0 + bb) * DD + n0;     // Vt rows (pitch SS)

  f32x4 acc[4][4];
#pragma unroll
  for (int i = 0; i < 4; ++i)
#pragma unroll
    for (int j = 0; j < 4; ++j)
      acc[i][j] = f32x4{0.f, 0.f, 0.f, 0.f};

  for (int k0 = 0; k0 < SS; k0 += 32) {
    stage_tile(Ah, P, arow0, SS, k0, wave, lane);
    stage_tile(Bh, Vt, brow0, SS, k0, wave, lane);
    __syncthreads();

    f16x8 ah[4], bh[4];
#pragma unroll
    for (int i = 0; i < 4; ++i) ah[i] = *(const f16x8*)&Ah[(wm + i * 16 + col) * 32 + quad * 8];
#pragma unroll
    for (int j = 0; j < 4; ++j) bh[j] = *(const f16x8*)&Bh[(wn + j * 16 + col) * 32 + quad * 8];
#pragma unroll
    for (int i = 0; i < 4; ++i)
#pragma unroll
      for (int j = 0; j < 4; ++j)
        acc[i][j] = MFMA_F16(ah[i], bh[j], acc[i][j]);
    __syncthreads();
  }

#pragma unroll
  for (int i = 0; i < 4; ++i)
#pragma unroll
    for (int j = 0; j < 4; ++j)
#pragma unroll
      for (int r = 0; r < 4; ++r) {
        const int gm = m0 + wm + i * 16 + quad * 4 + r;
        const int gn = n0 + wn + j * 16 + col;
        out[((size_t)(b0 + bb) * SS + gm) * DD + gn] = acc[i][j][r];
      }
}

// ---------------------------------------------------------------------------
extern "C" void kernel_launch(void* const* d_in, const int* in_sizes, int n_in,
                              void* d_out, int out_size, void* d_ws, size_t ws_size,
                              hipStream_t stream)
{
  const float* t_out = (const float*)d_in[0];
  const float* c_out = (const float*)d_in[1];
  const float* Wq    = (const float*)d_in[2];
  const float* bq    = (const float*)d_in[3];
  const float* Wk    = (const float*)d_in[4];
  const float* bk    = (const float*)d_in[5];
  const float* Wv    = (const float*)d_in[6];
  const float* bv    = (const float*)d_in[7];
  float* out = (float*)d_out;

  // ---- sizes ----
  const size_t WELT  = (size_t)DD * DD;
  const size_t TD8   = (size_t)BB * SS * DD;             // 16.7M elems
  const size_t XH_B  = TD8 * sizeof(f16);                // 33.55 MB
  const size_t SC1_B = (size_t)SS * SS * sizeof(f16);    // 8.39 MB per batch

  // ---- pick Sc chunk c (pure function of ws_size -> graph-safe) ----
  const size_t FIXED = 3 * WELT * sizeof(f16) + 4 * XH_B;  // 140.5 MB
  int c = 2;
  for (int cand : {8, 4}) {
    size_t xsc = (size_t)cand * SC1_B;
    if (xsc < XH_B) xsc = XH_B;
    if (FIXED + xsc <= ws_size) { c = cand; break; }
  }
  size_t xsc_bytes = (size_t)c * SC1_B;
  if (xsc_bytes < XH_B) xsc_bytes = XH_B;

  // ---- layout: [W][Xh|Sc(alias)][Q][K][Vv][Vt] ----
  char* ws = (char*)d_ws;
  f16* Whq = (f16*)ws;
  f16* Whk = Whq + WELT;
  f16* Whv = Whk + WELT;
  char* XSc = (char*)(Whv + WELT);
  f16* Xh = (f16*)XSc;     // live during prep/proj
  f16* Sc = (f16*)XSc;     // live during attention chunks (aliases Xh)
  f16* Q  = (f16*)(XSc + xsc_bytes);
  f16* K  = Q  + TD8;
  f16* Vv = K  + TD8;
  f16* Vt = Vv + TD8;

  fused_prep<<<dim3(1024 + 16384), dim3(256), 0, stream>>>(
      Wq, Wk, Wv, t_out, c_out, Whq, Whk, Whv, Xh);
  proj_gemm<<<dim3(128, 8, 3), dim3(256), 0, stream>>>(
      Xh, Whq, Whk, Whv, bq, bk, bv, Q, K, Vv);
  transpose_v<<<dim3(32, 16, 8), dim3(256), 0, stream>>>(Vv, Vt);

  for (int b0 = 0; b0 < BB; b0 += c) {
    qk_gemm<<<dim3(16, 16, c), dim3(256), 0, stream>>>(Q, K, Sc, b0);
    softmax_rows<<<dim3(c * SS), dim3(256), 0, stream>>>(Sc);
    pv_gemm<<<dim3(8, 16, c), dim3(256), 0, stream>>>(Sc, Vt, out, b0);
  }
}